// Round 8
// baseline (230.588 us; speedup 1.0000x reference)
//
#include <hip/hip_runtime.h>

#define L_DIM 4096
#define C_DIM 256
#define B_DIM 4
#define NH 8
#define DK 32

// Folds softmax 1/sqrt(DK) AND log2(e) into Wq at staging time, so the
// attention kernel uses a single v_exp_f32 (exp2) per score.
#define QSCALE 0.25507694f   // (1/sqrt(32)) * log2(e)

typedef __bf16 bf16x8 __attribute__((ext_vector_type(8)));
typedef float  f32x4  __attribute__((ext_vector_type(4)));
typedef float  f32x16 __attribute__((ext_vector_type(16)));

// pack two f32 -> packed bf16 pair (round-to-nearest via +0x8000, then
// byte-perm). Correct nearest-rounding for finite sign-magnitude values.
static __device__ __forceinline__ unsigned pk_bf16(float lo, float hi) {
    unsigned a = __builtin_bit_cast(unsigned, lo) + 0x8000u;
    unsigned b = __builtin_bit_cast(unsigned, hi) + 0x8000u;
    return __builtin_amdgcn_perm(b, a, 0x07060302u);   // {b[31:16], a[31:16]}
}

// ---------------------------------------------------------------------------
// Kernel 0: x [B,C,L] fp32 -> xt [B,L,C] bf16 (tiled transpose through LDS).
// ---------------------------------------------------------------------------
__global__ __launch_bounds__(256) void transpose_x_kernel(
    const float* __restrict__ x, __bf16* __restrict__ xt)
{
    const int t  = threadIdx.x;
    const int l0 = blockIdx.x * 64;
    const int c0 = blockIdx.y * 64;
    const int b  = blockIdx.z;

    __shared__ __attribute__((aligned(16))) float T[64][65];

    {
        const int r  = t >> 2;
        const int lc = (t & 3) * 16;
        const float* xp = x + ((size_t)b * C_DIM + c0 + r) * L_DIM + l0 + lc;
        #pragma unroll
        for (int k = 0; k < 4; ++k)
            *(f32x4*)&T[r][lc + k * 4] = *(const f32x4*)(xp + k * 4);
    }
    __syncthreads();
    {
        const int l  = t >> 2;
        const int cc = (t & 3) * 16;
        unsigned u[8];
        #pragma unroll
        for (int i = 0; i < 8; ++i)
            u[i] = pk_bf16(T[cc + 2 * i][l], T[cc + 2 * i + 1][l]);
        __bf16* op = xt + ((size_t)b * L_DIM + l0 + l) * C_DIM + c0 + cc;
        *(uint4*)op       = make_uint4(u[0], u[1], u[2], u[3]);
        *(uint4*)(op + 8) = make_uint4(u[4], u[5], u[6], u[7]);
    }
}

// ---------------------------------------------------------------------------
// Kernel 1: Q/K/V projections as bf16 MFMA GEMM. Prefetch for chunk bk+1 is
// issued AFTER the second barrier so it overlaps the MFMA phase (the first
// barrier of the next chunk drains it -- needed there anyway).
// ---------------------------------------------------------------------------
__global__ __launch_bounds__(256) void proj_mfma_kernel(
    const __bf16* __restrict__ xt, const float* __restrict__ Wq,
    const float* __restrict__ Wk, const float* __restrict__ Wv,
    __bf16* __restrict__ Qb, __bf16* __restrict__ Kb, __bf16* __restrict__ Vb)
{
    const int t    = threadIdx.x;
    const int wave = t >> 6;
    const int lane = t & 63;
    const int n32  = lane & 31;
    const int hl   = lane >> 5;
    const int l0   = blockIdx.x * 128;
    const int ob   = blockIdx.y & 1;
    const int p    = blockIdx.y >> 1;   // 0=Q 1=K 2=V
    const int b    = blockIdx.z;
    const float* W = (p == 0) ? Wq : ((p == 1) ? Wk : Wv);
    const float sc = (p == 0) ? QSCALE : 1.0f;

    __shared__ __attribute__((aligned(16))) __bf16 Wt[128][72];  // [o][c]
    __shared__ __attribute__((aligned(16))) __bf16 Xs[128][72];  // [l][c]

    const int wo  = t >> 1, wcc = (t & 1) * 32;
    const int xl  = t >> 1, xcc = (t & 1) * 32;
    const float*  wg = W + (size_t)(ob * 128 + wo) * C_DIM + wcc;
    const __bf16* xg = xt + ((size_t)b * L_DIM + l0 + xl) * C_DIM + xcc;

    const int moff = (wave & 1) * 64;
    const int noff = (wave >> 1) * 64;

    f32x16 acc[2][2];
    #pragma unroll
    for (int i = 0; i < 2; ++i)
        #pragma unroll
        for (int j = 0; j < 2; ++j)
            #pragma unroll
            for (int r = 0; r < 16; ++r) acc[i][j][r] = 0.f;

    f32x4  wraw[8];
    bf16x8 xpr[4];
    #pragma unroll
    for (int k = 0; k < 8; ++k) wraw[k] = *(const f32x4*)(wg + k * 4);
    #pragma unroll
    for (int g = 0; g < 4; ++g) xpr[g] = *(const bf16x8*)(xg + g * 8);

    for (int bk = 0; bk < 4; ++bk) {
        __syncthreads();   // drains prev LDS reads AND in-flight prefetch
        #pragma unroll
        for (int g = 0; g < 4; ++g) {
            unsigned u0 = pk_bf16(wraw[g*2][0] * sc, wraw[g*2][1] * sc);
            unsigned u1 = pk_bf16(wraw[g*2][2] * sc, wraw[g*2][3] * sc);
            unsigned u2 = pk_bf16(wraw[g*2+1][0] * sc, wraw[g*2+1][1] * sc);
            unsigned u3 = pk_bf16(wraw[g*2+1][2] * sc, wraw[g*2+1][3] * sc);
            *(uint4*)&Wt[wo][wcc + g * 8] = make_uint4(u0, u1, u2, u3);
            *(bf16x8*)&Xs[xl][xcc + g * 8] = xpr[g];
        }
        __syncthreads();

        {   // prefetch next chunk: in flight during MFMAs (wraps, discarded)
            const int nbk = (bk + 1) & 3;
            #pragma unroll
            for (int k = 0; k < 8; ++k)
                wraw[k] = *(const f32x4*)(wg + nbk * 64 + k * 4);
            #pragma unroll
            for (int g = 0; g < 4; ++g)
                xpr[g] = *(const bf16x8*)(xg + nbk * 64 + g * 8);
        }

        #pragma unroll
        for (int ks = 0; ks < 4; ++ks) {
            bf16x8 a0 = *(const bf16x8*)&Wt[moff + n32     ][ks * 16 + hl * 8];
            bf16x8 a1 = *(const bf16x8*)&Wt[moff + 32 + n32][ks * 16 + hl * 8];
            bf16x8 b0 = *(const bf16x8*)&Xs[noff + n32     ][ks * 16 + hl * 8];
            bf16x8 b1 = *(const bf16x8*)&Xs[noff + 32 + n32][ks * 16 + hl * 8];
            acc[0][0] = __builtin_amdgcn_mfma_f32_32x32x16_bf16(a0, b0, acc[0][0], 0, 0, 0);
            acc[0][1] = __builtin_amdgcn_mfma_f32_32x32x16_bf16(a0, b1, acc[0][1], 0, 0, 0);
            acc[1][0] = __builtin_amdgcn_mfma_f32_32x32x16_bf16(a1, b0, acc[1][0], 0, 0, 0);
            acc[1][1] = __builtin_amdgcn_mfma_f32_32x32x16_bf16(a1, b1, acc[1][1], 0, 0, 0);
        }
    }

    #pragma unroll
    for (int mt = 0; mt < 2; ++mt) {
        const int o32 = ob * 128 + moff + mt * 32;
        const int h   = o32 >> 5;
        const int bh  = b * NH + h;
        #pragma unroll
        for (int nt = 0; nt < 2; ++nt) {
            const int l = l0 + noff + nt * 32 + n32;
            if (p < 2) {
                __bf16* out = ((p == 0) ? Qb : Kb) + ((size_t)bh * L_DIM + l) * DK;
                #pragma unroll
                for (int g = 0; g < 4; ++g) {
                    unsigned u0 = pk_bf16(acc[mt][nt][g*4],     acc[mt][nt][g*4+1]);
                    unsigned u1 = pk_bf16(acc[mt][nt][g*4+2],   acc[mt][nt][g*4+3]);
                    *(uint2*)(out + 4 * hl + 8 * g) = make_uint2(u0, u1);
                }
            } else {
                #pragma unroll
                for (int r = 0; r < 16; ++r) {
                    const int dk = (r & 3) + 4 * hl + 8 * (r >> 2);
                    Vb[((size_t)bh * DK + dk) * L_DIM + l] = (__bf16)acc[mt][nt][r];
                }
            }
        }
    }
}

// ---------------------------------------------------------------------------
// Kernel 2: flash attention, K-split x2. Row-sums are now LANE-LOCAL VALU
// adds (no lacc MFMAs, no ones frag): each lane's e[] covers 16 of the 32
// kpos rows for its q column; the other 16 live in lane^32 -> one shfl_xor
// at the end. Frees 32 AGPRs (unified file) -> 4 waves/SIMD residency.
// Prefetch issued after barrier 2 (overlaps compute).
// ---------------------------------------------------------------------------
__global__ __launch_bounds__(256) void attn_kernel(
    const __bf16* __restrict__ Q, const __bf16* __restrict__ K,
    const __bf16* __restrict__ V, __bf16* __restrict__ Op0,
    __bf16* __restrict__ Op1, float* __restrict__ Ls)
{
    const int tid   = threadIdx.x;
    const int wave  = tid >> 6;
    const int lane  = tid & 63;
    const int n32   = lane & 31;
    const int hl    = lane >> 5;
    const int h     = blockIdx.y;
    const int b     = blockIdx.z >> 1;
    const int khalf = blockIdx.z & 1;
    const int bh    = b * NH + h;
    const int q0    = blockIdx.x * 256 + wave * 64;
    const int kt0   = khalf * 32;

    __shared__ __attribute__((aligned(16))) __bf16 Ks[64][40];
    __shared__ __attribute__((aligned(16))) __bf16 Vs[32][72];

    bf16x8 qf[2][2];
    #pragma unroll
    for (int qt = 0; qt < 2; ++qt) {
        const __bf16* qp = Q + ((size_t)bh * L_DIM + q0 + qt * 32 + n32) * DK;
        qf[qt][0] = *(const bf16x8*)(qp + hl * 8);
        qf[qt][1] = *(const bf16x8*)(qp + 16 + hl * 8);
    }

    f32x16 oacc[2];
    float  lsum[2] = {0.f, 0.f};
    #pragma unroll
    for (int qt = 0; qt < 2; ++qt)
        #pragma unroll
        for (int r = 0; r < 16; ++r) oacc[qt][r] = 0.f;

    const f32x16 z16 = {};

    const __bf16* kg = K + (size_t)bh * L_DIM * DK + (tid >> 2) * DK + (tid & 3) * 8;
    const __bf16* vg = V + ((size_t)bh * DK + (tid >> 3)) * L_DIM + (tid & 7) * 8;
    __bf16* ksd = &Ks[tid >> 2][(tid & 3) * 8];
    const int va  = tid & 7;
    __bf16* vsd0 = &Vs[tid >> 3][(va >> 1) * 16 + (va & 1) * 4];
    __bf16* vsd1 = vsd0 + 8;

    bf16x8 kreg = *(const bf16x8*)(kg + (size_t)kt0 * 64 * DK);
    bf16x8 vreg = *(const bf16x8*)(vg + kt0 * 64);

    for (int kt = 0; kt < 32; ++kt) {
        __syncthreads();   // drains prev LDS reads AND the in-flight prefetch
        *(bf16x8*)ksd = kreg;
        union { bf16x8 v; uint2 u2[2]; } vv; vv.v = vreg;
        *(uint2*)vsd0 = vv.u2[0];
        *(uint2*)vsd1 = vv.u2[1];
        __syncthreads();

        {   // prefetch next tile (wraps within half; overlaps compute)
            const int nkt = kt0 + ((kt + 1) & 31);
            kreg = *(const bf16x8*)(kg + (size_t)nkt * 64 * DK);
            vreg = *(const bf16x8*)(vg + nkt * 64);
        }

        bf16x8 kf[2][2];
        kf[0][0] = *(const bf16x8*)&Ks[n32     ][hl * 8];
        kf[0][1] = *(const bf16x8*)&Ks[n32     ][16 + hl * 8];
        kf[1][0] = *(const bf16x8*)&Ks[32 + n32][hl * 8];
        kf[1][1] = *(const bf16x8*)&Ks[32 + n32][16 + hl * 8];
        bf16x8 vf[4];
        vf[0] = *(const bf16x8*)&Vs[n32][     hl * 8];
        vf[1] = *(const bf16x8*)&Vs[n32][16 + hl * 8];
        vf[2] = *(const bf16x8*)&Vs[n32][32 + hl * 8];
        vf[3] = *(const bf16x8*)&Vs[n32][48 + hl * 8];

        #pragma unroll
        for (int mt = 0; mt < 2; ++mt) {
            #pragma unroll
            for (int qt = 0; qt < 2; ++qt) {
                f32x16 s = __builtin_amdgcn_mfma_f32_32x32x16_bf16(
                    kf[mt][0], qf[qt][0], z16, 0, 0, 0);
                s = __builtin_amdgcn_mfma_f32_32x32x16_bf16(
                    kf[mt][1], qf[qt][1], s, 0, 0, 0);

                float e[16];
                #pragma unroll
                for (int r = 0; r < 16; ++r) e[r] = __builtin_amdgcn_exp2f(s[r]);
                union { unsigned u[4]; bf16x8 v; } p0, p1;
                #pragma unroll
                for (int i = 0; i < 4; ++i) {
                    p0.u[i] = pk_bf16(e[2 * i],     e[2 * i + 1]);
                    p1.u[i] = pk_bf16(e[8 + 2 * i], e[8 + 2 * i + 1]);
                }
                // lane-local partial row-sum (16 of 32 kpos; rest in lane^32)
                lsum[qt] += (((e[0]+e[1])+(e[2]+e[3]))+((e[4]+e[5])+(e[6]+e[7])))
                          + (((e[8]+e[9])+(e[10]+e[11]))+((e[12]+e[13])+(e[14]+e[15])));

                oacc[qt] = __builtin_amdgcn_mfma_f32_32x32x16_bf16(
                    vf[mt * 2],     p0.v, oacc[qt], 0, 0, 0);
                oacc[qt] = __builtin_amdgcn_mfma_f32_32x32x16_bf16(
                    vf[mt * 2 + 1], p1.v, oacc[qt], 0, 0, 0);
            }
        }
    }

    // epilogue: complete row-sums across the lane pair, store O-half + lsum
    __bf16* Op = khalf ? Op1 : Op0;
    #pragma unroll
    for (int qt = 0; qt < 2; ++qt) {
        const float ltot = lsum[qt] + __shfl_xor(lsum[qt], 32);
        const int l = q0 + qt * 32 + n32;
        __bf16* ap = Op + ((size_t)b * L_DIM + l) * C_DIM + h * 32 + 4 * hl;
        #pragma unroll
        for (int g = 0; g < 4; ++g) {
            *(uint2*)(ap + 8 * g) = make_uint2(
                pk_bf16(oacc[qt][g*4],     oacc[qt][g*4+1]),
                pk_bf16(oacc[qt][g*4+2],   oacc[qt][g*4+3]));
        }
        Ls[((size_t)khalf * B_DIM * NH + bh) * L_DIM + l] = ltot;
    }
}

// ---------------------------------------------------------------------------
// Kernel 3: final projection as bf16 MFMA GEMM with the K-split combine
// fused into staging: at = relu((O1+O2)/(l1+l2)). Prefetch after barrier 2.
// ---------------------------------------------------------------------------
__global__ __launch_bounds__(256) void final_mfma_kernel(
    const __bf16* __restrict__ Op0, const __bf16* __restrict__ Op1,
    const float* __restrict__ Ls, const float* __restrict__ Wl,
    float* __restrict__ y)
{
    const int t    = threadIdx.x;
    const int wave = t >> 6;
    const int lane = t & 63;
    const int n32  = lane & 31;
    const int hl   = lane >> 5;
    const int l0   = blockIdx.x * 64;
    const int ob   = blockIdx.y;
    const int b    = blockIdx.z;

    __shared__ __attribute__((aligned(16))) __bf16 Wt[128][72];
    __shared__ __attribute__((aligned(16))) __bf16 Xs[64][72];

    const int wo  = t >> 1, wcc = (t & 1) * 32;
    const int xl  = t >> 2, xcc = (t & 3) * 16;
    const float* wg = Wl + (size_t)(ob * 128 + wo) * C_DIM + wcc;
    const size_t obase = ((size_t)b * L_DIM + l0 + xl) * C_DIM + xcc;

    float inv[4];
    {
        const int lidx = l0 + xl;
        #pragma unroll
        for (int bk = 0; bk < 4; ++bk) {
            const int hh = (bk * 64 + xcc) >> 5;
            const float l1 = Ls[((size_t)0 * B_DIM * NH + b * NH + hh) * L_DIM + lidx];
            const float l2 = Ls[((size_t)1 * B_DIM * NH + b * NH + hh) * L_DIM + lidx];
            inv[bk] = __builtin_amdgcn_rcpf(l1 + l2);
        }
    }

    const int moff = (wave & 1) * 64;
    const int noff = (wave >> 1) * 32;

    f32x16 acc[2];
    #pragma unroll
    for (int i = 0; i < 2; ++i)
        #pragma unroll
        for (int r = 0; r < 16; ++r) acc[i][r] = 0.f;

    f32x4  wraw[8];
    bf16x8 o1r, o2r, o1r2, o2r2;
    #pragma unroll
    for (int k = 0; k < 8; ++k) wraw[k] = *(const f32x4*)(wg + k * 4);
    o1r  = *(const bf16x8*)(Op0 + obase);
    o2r  = *(const bf16x8*)(Op1 + obase);
    o1r2 = *(const bf16x8*)(Op0 + obase + 8);
    o2r2 = *(const bf16x8*)(Op1 + obase + 8);

    for (int bk = 0; bk < 4; ++bk) {
        __syncthreads();
        #pragma unroll
        for (int g = 0; g < 4; ++g) {
            unsigned u0 = pk_bf16(wraw[g*2][0], wraw[g*2][1]);
            unsigned u1 = pk_bf16(wraw[g*2][2], wraw[g*2][3]);
            unsigned u2 = pk_bf16(wraw[g*2+1][0], wraw[g*2+1][1]);
            unsigned u3 = pk_bf16(wraw[g*2+1][2], wraw[g*2+1][3]);
            *(uint4*)&Wt[wo][wcc + g * 8] = make_uint4(u0, u1, u2, u3);
        }
        {
            unsigned u[4];
            #pragma unroll
            for (int i = 0; i < 4; ++i) {
                float v0 = ((float)o1r[2*i]   + (float)o2r[2*i]  ) * inv[bk];
                float v1 = ((float)o1r[2*i+1] + (float)o2r[2*i+1]) * inv[bk];
                v0 = v0 > 0.f ? v0 : 0.f;
                v1 = v1 > 0.f ? v1 : 0.f;
                u[i] = pk_bf16(v0, v1);
            }
            *(uint4*)&Xs[xl][xcc] = make_uint4(u[0], u[1], u[2], u[3]);
            #pragma unroll
            for (int i = 0; i < 4; ++i) {
                float v0 = ((float)o1r2[2*i]   + (float)o2r2[2*i]  ) * inv[bk];
                float v1 = ((float)o1r2[2*i+1] + (float)o2r2[2*i+1]) * inv[bk];
                v0 = v0 > 0.f ? v0 : 0.f;
                v1 = v1 > 0.f ? v1 : 0.f;
                u[i] = pk_bf16(v0, v1);
            }
            *(uint4*)&Xs[xl][xcc + 8] = make_uint4(u[0], u[1], u[2], u[3]);
        }
        __syncthreads();

        {   // prefetch next chunk (wraps; overlaps MFMAs)
            const int nbk = (bk + 1) & 3;
            #pragma unroll
            for (int k = 0; k < 8; ++k)
                wraw[k] = *(const f32x4*)(wg + nbk * 64 + k * 4);
            o1r  = *(const bf16x8*)(Op0 + obase + nbk * 64);
            o2r  = *(const bf16x8*)(Op1 + obase + nbk * 64);
            o1r2 = *(const bf16x8*)(Op0 + obase + nbk * 64 + 8);
            o2r2 = *(const bf16x8*)(Op1 + obase + nbk * 64 + 8);
        }

        #pragma unroll
        for (int ks = 0; ks < 4; ++ks) {
            bf16x8 a0 = *(const bf16x8*)&Wt[moff + n32     ][ks * 16 + hl * 8];
            bf16x8 a1 = *(const bf16x8*)&Wt[moff + 32 + n32][ks * 16 + hl * 8];
            bf16x8 b0 = *(const bf16x8*)&Xs[noff + n32     ][ks * 16 + hl * 8];
            acc[0] = __builtin_amdgcn_mfma_f32_32x32x16_bf16(a0, b0, acc[0], 0, 0, 0);
            acc[1] = __builtin_amdgcn_mfma_f32_32x32x16_bf16(a1, b0, acc[1], 0, 0, 0);
        }
    }

    #pragma unroll
    for (int mt = 0; mt < 2; ++mt) {
        #pragma unroll
        for (int r = 0; r < 16; ++r) {
            const int o = ob * 128 + moff + mt * 32 + (r & 3) + 4 * hl + 8 * (r >> 2);
            y[((size_t)b * C_DIM + o) * L_DIM + l0 + noff + n32] = acc[mt][r];
        }
    }
}

// ---------------------------------------------------------------------------
extern "C" void kernel_launch(void* const* d_in, const int* in_sizes, int n_in,
                              void* d_out, int out_size, void* d_ws, size_t ws_size,
                              hipStream_t stream)
{
    const float* x  = (const float*)d_in[0];
    const float* Wq = (const float*)d_in[1];
    const float* Wk = (const float*)d_in[2];
    const float* Wv = (const float*)d_in[3];
    const float* Wl = (const float*)d_in[4];
    float* y = (float*)d_out;

    const size_t n = (size_t)B_DIM * NH * L_DIM * DK;   // 4,194,304 elems
    __bf16* Qb  = (__bf16*)d_ws;          // [B,H,L,DK]
    __bf16* Kb  = Qb + n;
    __bf16* Vb  = Kb + n;                 // [B,H,DK,L]
    __bf16* Xt  = Vb + n;                 // [B,L,C]; dead after proj
    __bf16* Op0 = Xt;                     // aliases Xt: O-half 0, [B,L,C]
    __bf16* Op1 = Xt + n;                 // O-half 1
    float*  Ls  = (float*)(Op1 + n);      // [2][B*NH][L] exp-sums

    transpose_x_kernel<<<dim3(L_DIM/64, C_DIM/64, B_DIM), 256, 0, stream>>>(x, Xt);
    proj_mfma_kernel<<<dim3(L_DIM/128, 6, B_DIM), 256, 0, stream>>>(
        Xt, Wq, Wk, Wv, Qb, Kb, Vb);
    attn_kernel<<<dim3(L_DIM/256, NH, B_DIM * 2), 256, 0, stream>>>(
        Qb, Kb, Vb, Op0, Op1, Ls);
    final_mfma_kernel<<<dim3(L_DIM/64, 2, B_DIM), 256, 0, stream>>>(
        Op0, Op1, Ls, Wl, y);
}

// Round 9
// 216.799 us; speedup vs baseline: 1.0636x; 1.0636x over previous
//
#include <hip/hip_runtime.h>

#define L_DIM 4096
#define C_DIM 256
#define B_DIM 4
#define NH 8
#define DK 32

// Folds softmax 1/sqrt(DK) AND log2(e) into Wq at staging time, so the
// attention kernel uses a single v_exp_f32 (exp2) per score.
#define QSCALE 0.25507694f   // (1/sqrt(32)) * log2(e)

typedef __bf16 bf16x8 __attribute__((ext_vector_type(8)));
typedef float  f32x4  __attribute__((ext_vector_type(4)));
typedef float  f32x16 __attribute__((ext_vector_type(16)));

// pack two f32 -> packed bf16 pair. gfx950 has single-instruction
// v_cvt_pk_bf16_f32; fall back to add+perm RTNE sequence if unavailable.
#if defined(__has_builtin) && __has_builtin(__builtin_amdgcn_cvt_pk_bf16_f32)
static __device__ __forceinline__ unsigned pk_bf16(float lo, float hi) {
    auto v = __builtin_amdgcn_cvt_pk_bf16_f32(lo, hi);
    unsigned u;
    __builtin_memcpy(&u, &v, 4);
    return u;
}
#else
static __device__ __forceinline__ unsigned pk_bf16(float lo, float hi) {
    unsigned a = __builtin_bit_cast(unsigned, lo) + 0x8000u;
    unsigned b = __builtin_bit_cast(unsigned, hi) + 0x8000u;
    return __builtin_amdgcn_perm(b, a, 0x07060302u);   // {b[31:16], a[31:16]}
}
#endif

// ---------------------------------------------------------------------------
// Kernel 0: x [B,C,L] fp32 -> xt [B,L,C] bf16 (tiled transpose through LDS).
// ---------------------------------------------------------------------------
__global__ __launch_bounds__(256) void transpose_x_kernel(
    const float* __restrict__ x, __bf16* __restrict__ xt)
{
    const int t  = threadIdx.x;
    const int l0 = blockIdx.x * 64;
    const int c0 = blockIdx.y * 64;
    const int b  = blockIdx.z;

    __shared__ __attribute__((aligned(16))) float T[64][65];

    {
        const int r  = t >> 2;
        const int lc = (t & 3) * 16;
        const float* xp = x + ((size_t)b * C_DIM + c0 + r) * L_DIM + l0 + lc;
        #pragma unroll
        for (int k = 0; k < 4; ++k)
            *(f32x4*)&T[r][lc + k * 4] = *(const f32x4*)(xp + k * 4);
    }
    __syncthreads();
    {
        const int l  = t >> 2;
        const int cc = (t & 3) * 16;
        unsigned u[8];
        #pragma unroll
        for (int i = 0; i < 8; ++i)
            u[i] = pk_bf16(T[cc + 2 * i][l], T[cc + 2 * i + 1][l]);
        __bf16* op = xt + ((size_t)b * L_DIM + l0 + l) * C_DIM + c0 + cc;
        *(uint4*)op       = make_uint4(u[0], u[1], u[2], u[3]);
        *(uint4*)(op + 8) = make_uint4(u[4], u[5], u[6], u[7]);
    }
}

// ---------------------------------------------------------------------------
// Kernel 1: Q/K/V projections as bf16 MFMA GEMM (round-7 structure).
// ---------------------------------------------------------------------------
__global__ __launch_bounds__(256) void proj_mfma_kernel(
    const __bf16* __restrict__ xt, const float* __restrict__ Wq,
    const float* __restrict__ Wk, const float* __restrict__ Wv,
    __bf16* __restrict__ Qb, __bf16* __restrict__ Kb, __bf16* __restrict__ Vb)
{
    const int t    = threadIdx.x;
    const int wave = t >> 6;
    const int lane = t & 63;
    const int n32  = lane & 31;
    const int hl   = lane >> 5;
    const int l0   = blockIdx.x * 128;
    const int ob   = blockIdx.y & 1;
    const int p    = blockIdx.y >> 1;   // 0=Q 1=K 2=V
    const int b    = blockIdx.z;
    const float* W = (p == 0) ? Wq : ((p == 1) ? Wk : Wv);
    const float sc = (p == 0) ? QSCALE : 1.0f;

    __shared__ __attribute__((aligned(16))) __bf16 Wt[128][72];  // [o][c]
    __shared__ __attribute__((aligned(16))) __bf16 Xs[128][72];  // [l][c]

    const int wo  = t >> 1, wcc = (t & 1) * 32;
    const int xl  = t >> 1, xcc = (t & 1) * 32;
    const float*  wg = W + (size_t)(ob * 128 + wo) * C_DIM + wcc;
    const __bf16* xg = xt + ((size_t)b * L_DIM + l0 + xl) * C_DIM + xcc;

    const int moff = (wave & 1) * 64;
    const int noff = (wave >> 1) * 64;

    f32x16 acc[2][2];
    #pragma unroll
    for (int i = 0; i < 2; ++i)
        #pragma unroll
        for (int j = 0; j < 2; ++j)
            #pragma unroll
            for (int r = 0; r < 16; ++r) acc[i][j][r] = 0.f;

    unsigned wpk[16];
    bf16x8   xpr[4];
    #pragma unroll
    for (int k = 0; k < 8; ++k) {
        f32x4 wv = *(const f32x4*)(wg + k * 4);
        wpk[k * 2]     = pk_bf16(wv[0] * sc, wv[1] * sc);
        wpk[k * 2 + 1] = pk_bf16(wv[2] * sc, wv[3] * sc);
    }
    #pragma unroll
    for (int g = 0; g < 4; ++g) xpr[g] = *(const bf16x8*)(xg + g * 8);

    for (int bk = 0; bk < 4; ++bk) {
        __syncthreads();
        #pragma unroll
        for (int g = 0; g < 4; ++g) {
            *(uint4*)&Wt[wo][wcc + g * 8] =
                make_uint4(wpk[g*4], wpk[g*4+1], wpk[g*4+2], wpk[g*4+3]);
            *(bf16x8*)&Xs[xl][xcc + g * 8] = xpr[g];
        }
        if (bk < 3) {
            #pragma unroll
            for (int k = 0; k < 8; ++k) {
                f32x4 wv = *(const f32x4*)(wg + (bk + 1) * 64 + k * 4);
                wpk[k * 2]     = pk_bf16(wv[0] * sc, wv[1] * sc);
                wpk[k * 2 + 1] = pk_bf16(wv[2] * sc, wv[3] * sc);
            }
            #pragma unroll
            for (int g = 0; g < 4; ++g)
                xpr[g] = *(const bf16x8*)(xg + (bk + 1) * 64 + g * 8);
        }
        __syncthreads();

        #pragma unroll
        for (int ks = 0; ks < 4; ++ks) {
            bf16x8 a0 = *(const bf16x8*)&Wt[moff + n32     ][ks * 16 + hl * 8];
            bf16x8 a1 = *(const bf16x8*)&Wt[moff + 32 + n32][ks * 16 + hl * 8];
            bf16x8 b0 = *(const bf16x8*)&Xs[noff + n32     ][ks * 16 + hl * 8];
            bf16x8 b1 = *(const bf16x8*)&Xs[noff + 32 + n32][ks * 16 + hl * 8];
            acc[0][0] = __builtin_amdgcn_mfma_f32_32x32x16_bf16(a0, b0, acc[0][0], 0, 0, 0);
            acc[0][1] = __builtin_amdgcn_mfma_f32_32x32x16_bf16(a0, b1, acc[0][1], 0, 0, 0);
            acc[1][0] = __builtin_amdgcn_mfma_f32_32x32x16_bf16(a1, b0, acc[1][0], 0, 0, 0);
            acc[1][1] = __builtin_amdgcn_mfma_f32_32x32x16_bf16(a1, b1, acc[1][1], 0, 0, 0);
        }
    }

    #pragma unroll
    for (int mt = 0; mt < 2; ++mt) {
        const int o32 = ob * 128 + moff + mt * 32;
        const int h   = o32 >> 5;
        const int bh  = b * NH + h;
        #pragma unroll
        for (int nt = 0; nt < 2; ++nt) {
            const int l = l0 + noff + nt * 32 + n32;
            if (p < 2) {
                __bf16* out = ((p == 0) ? Qb : Kb) + ((size_t)bh * L_DIM + l) * DK;
                #pragma unroll
                for (int g = 0; g < 4; ++g) {
                    unsigned u0 = pk_bf16(acc[mt][nt][g*4],     acc[mt][nt][g*4+1]);
                    unsigned u1 = pk_bf16(acc[mt][nt][g*4+2],   acc[mt][nt][g*4+3]);
                    *(uint2*)(out + 4 * hl + 8 * g) = make_uint2(u0, u1);
                }
            } else {
                #pragma unroll
                for (int r = 0; r < 16; ++r) {
                    const int dk = (r & 3) + 4 * hl + 8 * (r >> 2);
                    Vb[((size_t)bh * DK + dk) * L_DIM + l] = (__bf16)acc[mt][nt][r];
                }
            }
        }
    }
}

// ---------------------------------------------------------------------------
// Kernel 2: flash attention, K-split x2, round-7 structure: row-sums via
// ones-MFMA (lacc) — MFMA pipe has spare capacity, VALU is the bottleneck.
// Epilogue stores UNNORMALIZED O-half + exp-sum; combine fused in final GEMM.
// ---------------------------------------------------------------------------
__global__ __launch_bounds__(256) void attn_kernel(
    const __bf16* __restrict__ Q, const __bf16* __restrict__ K,
    const __bf16* __restrict__ V, __bf16* __restrict__ Op0,
    __bf16* __restrict__ Op1, float* __restrict__ Ls)
{
    const int tid   = threadIdx.x;
    const int wave  = tid >> 6;
    const int lane  = tid & 63;
    const int n32   = lane & 31;
    const int hl    = lane >> 5;
    const int h     = blockIdx.y;
    const int b     = blockIdx.z >> 1;
    const int khalf = blockIdx.z & 1;
    const int bh    = b * NH + h;
    const int q0    = blockIdx.x * 256 + wave * 64;
    const int kt0   = khalf * 32;      // this block's 32 KV tiles

    __shared__ __attribute__((aligned(16))) __bf16 Ks[64][40];
    __shared__ __attribute__((aligned(16))) __bf16 Vs[32][72];

    bf16x8 qf[2][2];
    #pragma unroll
    for (int qt = 0; qt < 2; ++qt) {
        const __bf16* qp = Q + ((size_t)bh * L_DIM + q0 + qt * 32 + n32) * DK;
        qf[qt][0] = *(const bf16x8*)(qp + hl * 8);
        qf[qt][1] = *(const bf16x8*)(qp + 16 + hl * 8);
    }

    f32x16 oacc[2], lacc[2];
    #pragma unroll
    for (int qt = 0; qt < 2; ++qt)
        #pragma unroll
        for (int r = 0; r < 16; ++r) { oacc[qt][r] = 0.f; lacc[qt][r] = 0.f; }

    const f32x16 z16 = {};

    bf16x8 ones;
    #pragma unroll
    for (int j = 0; j < 8; ++j) ones[j] = (__bf16)1.0f;

    const __bf16* kg = K + (size_t)bh * L_DIM * DK + (tid >> 2) * DK + (tid & 3) * 8;
    const __bf16* vg = V + ((size_t)bh * DK + (tid >> 3)) * L_DIM + (tid & 7) * 8;
    __bf16* ksd = &Ks[tid >> 2][(tid & 3) * 8];
    const int va  = tid & 7;
    __bf16* vsd0 = &Vs[tid >> 3][(va >> 1) * 16 + (va & 1) * 4];
    __bf16* vsd1 = vsd0 + 8;

    bf16x8 kreg = *(const bf16x8*)(kg + (size_t)kt0 * 64 * DK);
    bf16x8 vreg = *(const bf16x8*)(vg + kt0 * 64);

    for (int kt = 0; kt < 32; ++kt) {
        __syncthreads();
        *(bf16x8*)ksd = kreg;
        union { bf16x8 v; uint2 u2[2]; } vv; vv.v = vreg;
        *(uint2*)vsd0 = vv.u2[0];
        *(uint2*)vsd1 = vv.u2[1];
        {   // branchless prefetch (wraps within the half, discarded on last)
            const int nkt = kt0 + ((kt + 1) & 31);
            kreg = *(const bf16x8*)(kg + (size_t)nkt * 64 * DK);
            vreg = *(const bf16x8*)(vg + nkt * 64);
        }
        __syncthreads();

        bf16x8 kf[2][2];
        kf[0][0] = *(const bf16x8*)&Ks[n32     ][hl * 8];
        kf[0][1] = *(const bf16x8*)&Ks[n32     ][16 + hl * 8];
        kf[1][0] = *(const bf16x8*)&Ks[32 + n32][hl * 8];
        kf[1][1] = *(const bf16x8*)&Ks[32 + n32][16 + hl * 8];
        bf16x8 vf[4];
        vf[0] = *(const bf16x8*)&Vs[n32][     hl * 8];
        vf[1] = *(const bf16x8*)&Vs[n32][16 + hl * 8];
        vf[2] = *(const bf16x8*)&Vs[n32][32 + hl * 8];
        vf[3] = *(const bf16x8*)&Vs[n32][48 + hl * 8];

        #pragma unroll
        for (int mt = 0; mt < 2; ++mt) {
            #pragma unroll
            for (int qt = 0; qt < 2; ++qt) {
                f32x16 s = __builtin_amdgcn_mfma_f32_32x32x16_bf16(
                    kf[mt][0], qf[qt][0], z16, 0, 0, 0);
                s = __builtin_amdgcn_mfma_f32_32x32x16_bf16(
                    kf[mt][1], qf[qt][1], s, 0, 0, 0);

                float e[16];
                #pragma unroll
                for (int r = 0; r < 16; ++r) e[r] = __builtin_amdgcn_exp2f(s[r]);
                union { unsigned u[4]; bf16x8 v; } p0, p1;
                #pragma unroll
                for (int i = 0; i < 4; ++i) {
                    p0.u[i] = pk_bf16(e[2 * i],     e[2 * i + 1]);
                    p1.u[i] = pk_bf16(e[8 + 2 * i], e[8 + 2 * i + 1]);
                }

                oacc[qt] = __builtin_amdgcn_mfma_f32_32x32x16_bf16(
                    vf[mt * 2],     p0.v, oacc[qt], 0, 0, 0);
                lacc[qt] = __builtin_amdgcn_mfma_f32_32x32x16_bf16(
                    ones,           p0.v, lacc[qt], 0, 0, 0);
                oacc[qt] = __builtin_amdgcn_mfma_f32_32x32x16_bf16(
                    vf[mt * 2 + 1], p1.v, oacc[qt], 0, 0, 0);
                lacc[qt] = __builtin_amdgcn_mfma_f32_32x32x16_bf16(
                    ones,           p1.v, lacc[qt], 0, 0, 0);
            }
        }
    }

    // epilogue: unnormalized O-half -> Op[khalf] in [B,L,C] layout; lsum -> Ls
    __bf16* Op = khalf ? Op1 : Op0;
    #pragma unroll
    for (int qt = 0; qt < 2; ++qt) {
        const int l = q0 + qt * 32 + n32;
        __bf16* ap = Op + ((size_t)b * L_DIM + l) * C_DIM + h * 32 + 4 * hl;
        #pragma unroll
        for (int g = 0; g < 4; ++g) {
            *(uint2*)(ap + 8 * g) = make_uint2(
                pk_bf16(oacc[qt][g*4],     oacc[qt][g*4+1]),
                pk_bf16(oacc[qt][g*4+2],   oacc[qt][g*4+3]));
        }
        Ls[((size_t)khalf * B_DIM * NH + bh) * L_DIM + l] = lacc[qt][0];
    }
}

// ---------------------------------------------------------------------------
// Kernel 3: final projection as bf16 MFMA GEMM with the K-split combine
// fused into staging: at = relu((O1+O2)/(l1+l2)).
// ---------------------------------------------------------------------------
__global__ __launch_bounds__(256) void final_mfma_kernel(
    const __bf16* __restrict__ Op0, const __bf16* __restrict__ Op1,
    const float* __restrict__ Ls, const float* __restrict__ Wl,
    float* __restrict__ y)
{
    const int t    = threadIdx.x;
    const int wave = t >> 6;
    const int lane = t & 63;
    const int n32  = lane & 31;
    const int hl   = lane >> 5;
    const int l0   = blockIdx.x * 64;
    const int ob   = blockIdx.y;
    const int b    = blockIdx.z;

    __shared__ __attribute__((aligned(16))) __bf16 Wt[128][72];
    __shared__ __attribute__((aligned(16))) __bf16 Xs[64][72];

    const int wo  = t >> 1, wcc = (t & 1) * 32;
    const int xl  = t >> 2, xcc = (t & 3) * 16;
    const float* wg = Wl + (size_t)(ob * 128 + wo) * C_DIM + wcc;
    const size_t obase = ((size_t)b * L_DIM + l0 + xl) * C_DIM + xcc;

    float inv[4];
    {
        const int lidx = l0 + xl;
        #pragma unroll
        for (int bk = 0; bk < 4; ++bk) {
            const int hh = (bk * 64 + xcc) >> 5;
            const float l1 = Ls[((size_t)0 * B_DIM * NH + b * NH + hh) * L_DIM + lidx];
            const float l2 = Ls[((size_t)1 * B_DIM * NH + b * NH + hh) * L_DIM + lidx];
            inv[bk] = __builtin_amdgcn_rcpf(l1 + l2);
        }
    }

    const int moff = (wave & 1) * 64;
    const int noff = (wave >> 1) * 32;

    f32x16 acc[2];
    #pragma unroll
    for (int i = 0; i < 2; ++i)
        #pragma unroll
        for (int r = 0; r < 16; ++r) acc[i][r] = 0.f;

    unsigned wpk[16];
    bf16x8   o1r, o2r, o1r2, o2r2;
    #pragma unroll
    for (int k = 0; k < 8; ++k) {
        f32x4 wv = *(const f32x4*)(wg + k * 4);
        wpk[k * 2]     = pk_bf16(wv[0], wv[1]);
        wpk[k * 2 + 1] = pk_bf16(wv[2], wv[3]);
    }
    o1r  = *(const bf16x8*)(Op0 + obase);
    o2r  = *(const bf16x8*)(Op1 + obase);
    o1r2 = *(const bf16x8*)(Op0 + obase + 8);
    o2r2 = *(const bf16x8*)(Op1 + obase + 8);

    for (int bk = 0; bk < 4; ++bk) {
        __syncthreads();
        #pragma unroll
        for (int g = 0; g < 4; ++g)
            *(uint4*)&Wt[wo][wcc + g * 8] =
                make_uint4(wpk[g*4], wpk[g*4+1], wpk[g*4+2], wpk[g*4+3]);
        {   // combine halves: relu((O1+O2)*inv) -> bf16 fragment row
            unsigned u[4];
            #pragma unroll
            for (int i = 0; i < 4; ++i) {
                float v0 = ((float)o1r[2*i]   + (float)o2r[2*i]  ) * inv[bk];
                float v1 = ((float)o1r[2*i+1] + (float)o2r[2*i+1]) * inv[bk];
                v0 = v0 > 0.f ? v0 : 0.f;
                v1 = v1 > 0.f ? v1 : 0.f;
                u[i] = pk_bf16(v0, v1);
            }
            *(uint4*)&Xs[xl][xcc] = make_uint4(u[0], u[1], u[2], u[3]);
            #pragma unroll
            for (int i = 0; i < 4; ++i) {
                float v0 = ((float)o1r2[2*i]   + (float)o2r2[2*i]  ) * inv[bk];
                float v1 = ((float)o1r2[2*i+1] + (float)o2r2[2*i+1]) * inv[bk];
                v0 = v0 > 0.f ? v0 : 0.f;
                v1 = v1 > 0.f ? v1 : 0.f;
                u[i] = pk_bf16(v0, v1);
            }
            *(uint4*)&Xs[xl][xcc + 8] = make_uint4(u[0], u[1], u[2], u[3]);
        }
        if (bk < 3) {
            #pragma unroll
            for (int k = 0; k < 8; ++k) {
                f32x4 wv = *(const f32x4*)(wg + (bk + 1) * 64 + k * 4);
                wpk[k * 2]     = pk_bf16(wv[0], wv[1]);
                wpk[k * 2 + 1] = pk_bf16(wv[2], wv[3]);
            }
            o1r  = *(const bf16x8*)(Op0 + obase + (bk + 1) * 64);
            o2r  = *(const bf16x8*)(Op1 + obase + (bk + 1) * 64);
            o1r2 = *(const bf16x8*)(Op0 + obase + (bk + 1) * 64 + 8);
            o2r2 = *(const bf16x8*)(Op1 + obase + (bk + 1) * 64 + 8);
        }
        __syncthreads();

        #pragma unroll
        for (int ks = 0; ks < 4; ++ks) {
            bf16x8 a0 = *(const bf16x8*)&Wt[moff + n32     ][ks * 16 + hl * 8];
            bf16x8 a1 = *(const bf16x8*)&Wt[moff + 32 + n32][ks * 16 + hl * 8];
            bf16x8 b0 = *(const bf16x8*)&Xs[noff + n32     ][ks * 16 + hl * 8];
            acc[0] = __builtin_amdgcn_mfma_f32_32x32x16_bf16(a0, b0, acc[0], 0, 0, 0);
            acc[1] = __builtin_amdgcn_mfma_f32_32x32x16_bf16(a1, b0, acc[1], 0, 0, 0);
        }
    }

    #pragma unroll
    for (int mt = 0; mt < 2; ++mt) {
        #pragma unroll
        for (int r = 0; r < 16; ++r) {
            const int o = ob * 128 + moff + mt * 32 + (r & 3) + 4 * hl + 8 * (r >> 2);
            y[((size_t)b * C_DIM + o) * L_DIM + l0 + noff + n32] = acc[mt][r];
        }
    }
}

// ---------------------------------------------------------------------------
extern "C" void kernel_launch(void* const* d_in, const int* in_sizes, int n_in,
                              void* d_out, int out_size, void* d_ws, size_t ws_size,
                              hipStream_t stream)
{
    const float* x  = (const float*)d_in[0];
    const float* Wq = (const float*)d_in[1];
    const float* Wk = (const float*)d_in[2];
    const float* Wv = (const float*)d_in[3];
    const float* Wl = (const float*)d_in[4];
    float* y = (float*)d_out;

    const size_t n = (size_t)B_DIM * NH * L_DIM * DK;   // 4,194,304 elems
    __bf16* Qb  = (__bf16*)d_ws;          // [B,H,L,DK]
    __bf16* Kb  = Qb + n;
    __bf16* Vb  = Kb + n;                 // [B,H,DK,L]
    __bf16* Xt  = Vb + n;                 // [B,L,C]; dead after proj
    __bf16* Op0 = Xt;                     // aliases Xt: O-half 0, [B,L,C]
    __bf16* Op1 = Xt + n;                 // O-half 1
    float*  Ls  = (float*)(Op1 + n);      // [2][B*NH][L] exp-sums

    transpose_x_kernel<<<dim3(L_DIM/64, C_DIM/64, B_DIM), 256, 0, stream>>>(x, Xt);
    proj_mfma_kernel<<<dim3(L_DIM/128, 6, B_DIM), 256, 0, stream>>>(
        Xt, Wq, Wk, Wv, Qb, Kb, Vb);
    attn_kernel<<<dim3(L_DIM/256, NH, B_DIM * 2), 256, 0, stream>>>(
        Qb, Kb, Vb, Op0, Op1, Ls);
    final_mfma_kernel<<<dim3(L_DIM/64, 2, B_DIM), 256, 0, stream>>>(
        Op0, Op1, Ls, Wl, y);
}